// Round 5
// baseline (93.309 us; speedup 1.0000x reference)
//
#include <hip/hip_runtime.h>
#include <cmath>

constexpr int D    = 512;
constexpr int NC   = 225;   // classes
constexpr int NCP  = 232;   // padded classes (mult of 8)
constexpr int NPC  = 224;   // outputs per class
constexpr int TB   = 32;    // tokens per chunk
constexpr int XST  = 516;   // xs row stride: 516%32==4 -> per-row bank offset 4; 16B aligned

// ws layout (int units)
constexpr int WS_NCHUNK = 0;        // 1
constexpr int WS_ORDER  = 256;      // 4096 token ids grouped by class
constexpr int WS_CHUNK  = 4608;     // up to 481*4 ints (cls,start,cnt,pad)
constexpr int WS_P1     = 7680;     // 4096 floats
constexpr int WS_P2     = 11776;    // 4096 floats
constexpr int WS_B1P    = 15872;    // 232 floats padded b1
constexpr int WS_W1P    = 16384;    // 512*232 floats padded W1

// ---------- prep: histogram + scans + chunk table (phase2 first) + scatter ----------
__global__ __launch_bounds__(256) void k_prep(const int* __restrict__ target,
                                              int* __restrict__ ws, int ntok) {
    __shared__ int h[256];
    __shared__ int sc[256];
    __shared__ int sc2[256];
    __shared__ int cur[NC];
    const int tid = threadIdx.x;
    h[tid] = 0;
    __syncthreads();
    for (int n = tid; n < ntok; n += 256) atomicAdd(&h[target[n] / NPC], 1);
    __syncthreads();
    const int hv = h[tid];
    sc[tid] = hv; __syncthreads();
    for (int o = 1; o < 256; o <<= 1) {
        int a = (tid >= o) ? sc[tid - o] : 0;
        __syncthreads();
        sc[tid] += a;
        __syncthreads();
    }
    const int start = sc[tid] - hv;                 // token offset of class tid
    const int nch = (tid < NC) ? (hv + TB - 1) / TB : 0;
    sc2[tid] = nch; __syncthreads();
    for (int o = 1; o < 256; o <<= 1) {
        int a = (tid >= o) ? sc2[tid - o] : 0;
        __syncthreads();
        sc2[tid] += a;
        __syncthreads();
    }
    const int nch2 = sc2[255];                      // total phase-2 chunks
    if (tid < NC) {
        cur[tid] = start;
        const int cb = sc2[tid] - nch;
        for (int j = 0; j < nch; ++j) {
            const int e = WS_CHUNK + (cb + j) * 4;
            ws[e + 0] = tid;
            ws[e + 1] = start + j * TB;
            ws[e + 2] = min(TB, hv - j * TB);
            ws[e + 3] = 0;
        }
    }
    const int P1C = ntok / TB;                      // phase-1 chunks (128)
    if (tid < P1C) {
        const int e = WS_CHUNK + (nch2 + tid) * 4;
        ws[e + 0] = -1;
        ws[e + 1] = tid * TB;
        ws[e + 2] = TB;
        ws[e + 3] = 0;
    }
    if (tid == 0) ws[WS_NCHUNK] = nch2 + P1C;
    __syncthreads();
    for (int n = tid; n < ntok; n += 256) {
        const int c = target[n] / NPC;
        const int pos = atomicAdd(&cur[c], 1);
        ws[WS_ORDER + pos] = n;
    }
}

// ---------- pad W1 (512x225 -> 512x232) and b1 into ws ----------
__global__ __launch_bounds__(256) void k_pad(const float* __restrict__ W1,
                                             const float* __restrict__ b1,
                                             int* __restrict__ ws) {
    float* W1p = (float*)ws + WS_W1P;
    float* b1p = (float*)ws + WS_B1P;
    const int idx = blockIdx.x * 256 + threadIdx.x;
    if (idx < D * NCP) {
        const int d = idx / NCP, c = idx % NCP;
        W1p[idx] = (c < NC) ? W1[d * NC + c] : 0.f;
    }
    if (blockIdx.x == 0 && threadIdx.x < NCP)
        b1p[threadIdx.x] = (threadIdx.x < NC) ? b1[threadIdx.x] : -1e30f;
}

// ---------- main: unified chunk GEMM + softmax ----------
// 256 threads, TB=32 tokens. Tile: 8 outputs x 8 tokens per thread, full K=512.
// og in [0,NOG), tg in [0,8); token rows of thread = tg + 8*i, i in [0,4).
__global__ __launch_bounds__(256) void k_main(
    const float* __restrict__ x, const int* __restrict__ target,
    const float* __restrict__ W2, const float* __restrict__ b2,
    int* __restrict__ ws)
{
    __shared__ float xs[TB][XST];   // x rows; logits written back after GEMM
    __shared__ int stok[TB];

    const int tid = threadIdx.x, bid = blockIdx.x;
    if (bid >= ws[WS_NCHUNK]) return;

    const int4 ce = *reinterpret_cast<const int4*>(ws + WS_CHUNK + bid * 4);
    const int cls = ce.x, start = ce.y, cnt = ce.z;
    const bool ph2 = (cls >= 0);
    const int NP = ph2 ? NPC : NCP;
    int og, tg;
    if (ph2) { og = tid % 28; tg = tid / 28; }
    else     { og = tid % 29; tg = tid / 29; }
    const float* wbase = ph2 ? (W2 + (size_t)cls * D * NPC)
                             : ((const float*)ws + WS_W1P);
    const float* bptr  = ph2 ? (b2 + cls * NPC)
                             : ((const float*)ws + WS_B1P);
    float* pout = (float*)ws + (ph2 ? WS_P2 : WS_P1);

    if (tid < TB)
        stok[tid] = ph2 ? ws[WS_ORDER + start + min(tid, cnt - 1)] : (start + tid);
    __syncthreads();

    // stage 32 x-rows (4096 float4, 16 per thread, coalesced)
    #pragma unroll
    for (int k = 0; k < 16; ++k) {
        const int f = tid + k * 256;
        const int row = f >> 7, col = f & 127;
        *reinterpret_cast<float4*>(&xs[row][col * 4]) =
            reinterpret_cast<const float4*>(x + (size_t)stok[row] * D)[col];
    }
    __syncthreads();

    const bool active = (tg < 8);

    float acc[8][4];
    #pragma unroll
    for (int j = 0; j < 8; ++j)
        #pragma unroll
        for (int i = 0; i < 4; ++i) acc[j][i] = 0.f;

    if (active) {
        const float* wp = wbase + og * 8;
        float4 wl0[4], wh0[4], wl1[4], wh1[4], xa[4], xb[4];

        #pragma unroll
        for (int k = 0; k < 4; ++k) {
            wl0[k] = *reinterpret_cast<const float4*>(wp + (size_t)k * NP);
            wh0[k] = *reinterpret_cast<const float4*>(wp + (size_t)k * NP + 4);
        }
        #pragma unroll
        for (int i = 0; i < 4; ++i)
            xa[i] = *reinterpret_cast<const float4*>(&xs[tg + 8 * i][0]);

        for (int d0 = 0; d0 < D; d0 += 8) {
            // prefetch group B (d0+4..d0+7)
            #pragma unroll
            for (int k = 0; k < 4; ++k) {
                wl1[k] = *reinterpret_cast<const float4*>(wp + (size_t)(k + 4) * NP);
                wh1[k] = *reinterpret_cast<const float4*>(wp + (size_t)(k + 4) * NP + 4);
            }
            #pragma unroll
            for (int i = 0; i < 4; ++i)
                xb[i] = *reinterpret_cast<const float4*>(&xs[tg + 8 * i][d0 + 4]);

            // FMA group A
            #pragma unroll
            for (int k = 0; k < 4; ++k) {
                #pragma unroll
                for (int i = 0; i < 4; ++i) {
                    const float xk = (&xa[i].x)[k];
                    acc[0][i] = fmaf(xk, wl0[k].x, acc[0][i]);
                    acc[1][i] = fmaf(xk, wl0[k].y, acc[1][i]);
                    acc[2][i] = fmaf(xk, wl0[k].z, acc[2][i]);
                    acc[3][i] = fmaf(xk, wl0[k].w, acc[3][i]);
                    acc[4][i] = fmaf(xk, wh0[k].x, acc[4][i]);
                    acc[5][i] = fmaf(xk, wh0[k].y, acc[5][i]);
                    acc[6][i] = fmaf(xk, wh0[k].z, acc[6][i]);
                    acc[7][i] = fmaf(xk, wh0[k].w, acc[7][i]);
                }
            }
            // prefetch group A of next macro-iter
            if (d0 + 8 < D) {
                #pragma unroll
                for (int k = 0; k < 4; ++k) {
                    wl0[k] = *reinterpret_cast<const float4*>(wp + (size_t)(k + 8) * NP);
                    wh0[k] = *reinterpret_cast<const float4*>(wp + (size_t)(k + 8) * NP + 4);
                }
                #pragma unroll
                for (int i = 0; i < 4; ++i)
                    xa[i] = *reinterpret_cast<const float4*>(&xs[tg + 8 * i][d0 + 8]);
            }
            // FMA group B
            #pragma unroll
            for (int k = 0; k < 4; ++k) {
                #pragma unroll
                for (int i = 0; i < 4; ++i) {
                    const float xk = (&xb[i].x)[k];
                    acc[0][i] = fmaf(xk, wl1[k].x, acc[0][i]);
                    acc[1][i] = fmaf(xk, wl1[k].y, acc[1][i]);
                    acc[2][i] = fmaf(xk, wl1[k].z, acc[2][i]);
                    acc[3][i] = fmaf(xk, wl1[k].w, acc[3][i]);
                    acc[4][i] = fmaf(xk, wh1[k].x, acc[4][i]);
                    acc[5][i] = fmaf(xk, wh1[k].y, acc[5][i]);
                    acc[6][i] = fmaf(xk, wh1[k].z, acc[6][i]);
                    acc[7][i] = fmaf(xk, wh1[k].w, acc[7][i]);
                }
            }
            wp += 8 * NP;
        }
    }
    __syncthreads();   // all xs reads done; reuse xs rows for logits

    if (active) {
        const float4 bl = *reinterpret_cast<const float4*>(bptr + og * 8);
        const float4 bh = *reinterpret_cast<const float4*>(bptr + og * 8 + 4);
        #pragma unroll
        for (int i = 0; i < 4; ++i) {
            const int row = tg + 8 * i;
            float4 lo = {acc[0][i] + bl.x, acc[1][i] + bl.y, acc[2][i] + bl.z, acc[3][i] + bl.w};
            float4 hi = {acc[4][i] + bh.x, acc[5][i] + bh.y, acc[6][i] + bh.z, acc[7][i] + bh.w};
            *reinterpret_cast<float4*>(&xs[row][og * 8])     = lo;
            *reinterpret_cast<float4*>(&xs[row][og * 8 + 4]) = hi;
        }
    }
    __syncthreads();

    // softmax: wave wv handles tokens wv*8 .. wv*8+7
    const int wv = tid >> 6, ln = tid & 63;
    #pragma unroll
    for (int s = 0; s < 8; ++s) {
        const int t = wv * 8 + s;
        float v0 = xs[t][ln];
        float v1 = xs[t][64 + ln];
        float v2 = xs[t][128 + ln];
        float v3 = (192 + ln < NP) ? xs[t][192 + ln] : -1e30f;
        float m = fmaxf(fmaxf(v0, v1), fmaxf(v2, v3));
        #pragma unroll
        for (int k = 32; k >= 1; k >>= 1) m = fmaxf(m, __shfl_xor(m, k, 64));
        float e = __expf(v0 - m) + __expf(v1 - m) + __expf(v2 - m) +
                  ((192 + ln < NP) ? __expf(v3 - m) : 0.f);
        #pragma unroll
        for (int k = 32; k >= 1; k >>= 1) e += __shfl_xor(e, k, 64);
        if (ln == 0 && t < cnt) {
            const int tok = stok[t];
            const int tt  = target[tok];
            const int col = ph2 ? (tt % NPC) : (tt / NPC);
            pout[tok] = __expf(xs[t][col] - m) / e;
        }
    }
}

// ---------- combine: out = p1 * p2 ----------
__global__ __launch_bounds__(256) void k_combine(const int* __restrict__ ws,
                                                 float* __restrict__ out, int ntok) {
    const int n = blockIdx.x * 256 + threadIdx.x;
    const float* p1 = (const float*)ws + WS_P1;
    const float* p2 = (const float*)ws + WS_P2;
    if (n < ntok) out[n] = p1[n] * p2[n];
}

extern "C" void kernel_launch(void* const* d_in, const int* in_sizes, int n_in,
                              void* d_out, int out_size, void* d_ws, size_t ws_size,
                              hipStream_t stream) {
    const float* x      = (const float*)d_in[0];
    const int*   target = (const int*)  d_in[1];
    const float* W1     = (const float*)d_in[2];
    const float* b1     = (const float*)d_in[3];
    const float* W2     = (const float*)d_in[4];
    const float* b2     = (const float*)d_in[5];
    float* out = (float*)d_out;
    int*   wsi = (int*)d_ws;

    const int ntok = in_sizes[1];                       // 4096
    // max chunks: phase2 <= ntok/TB + NC, phase1 = ntok/TB
    const int maxgrid = ntok / TB + NC + ntok / TB;     // 481

    k_prep   <<<1, 256, 0, stream>>>(target, wsi, ntok);
    k_pad    <<<(D * NCP + 255) / 256, 256, 0, stream>>>(W1, b1, wsi);
    k_main   <<<maxgrid, 256, 0, stream>>>(x, target, W2, b2, wsi);
    k_combine<<<(ntok + 255) / 256, 256, 0, stream>>>(wsi, out, ntok);
}